// Round 1
// baseline (6552.102 us; speedup 1.0000x reference)
//
#include <hip/hip_runtime.h>

#define NN   16384
#define DIM  256
#define KNN  16

// ======================================================================
// Generic fp32 GEMM:  C[M,NO] = act( rowscale(A[M,K] @ W[NO,K]^T) + bias )
// BM=BN=64, TK=16, 256 threads, 4x4 micro-tile.
// ======================================================================
template<bool RELU, bool BIAS, bool ROWSCALE>
__global__ __launch_bounds__(256)
void gemm_nt(const float* __restrict__ A, const float* __restrict__ W,
             const float* __restrict__ bias, const float* __restrict__ rscale,
             float* __restrict__ C, int M, int K, int NO)
{
    __shared__ __align__(16) float As[16][68];
    __shared__ __align__(16) float Ws[16][68];
    const int tid = threadIdx.x;
    const int tx = tid & 15, ty = tid >> 4;
    const int row0 = blockIdx.y * 64, col0 = blockIdx.x * 64;
    const int lr = tid >> 2;          // 0..63
    const int lk = (tid & 3) * 4;     // 0,4,8,12

    float acc[4][4] = {};

    for (int k0 = 0; k0 < K; k0 += 16) {
        float4 av = *(const float4*)&A[(size_t)(row0 + lr) * K + k0 + lk];
        float4 wv = *(const float4*)&W[(size_t)(col0 + lr) * K + k0 + lk];
        __syncthreads();
        As[lk+0][lr] = av.x; As[lk+1][lr] = av.y; As[lk+2][lr] = av.z; As[lk+3][lr] = av.w;
        Ws[lk+0][lr] = wv.x; Ws[lk+1][lr] = wv.y; Ws[lk+2][lr] = wv.z; Ws[lk+3][lr] = wv.w;
        __syncthreads();
        #pragma unroll
        for (int kk = 0; kk < 16; ++kk) {
            float4 a = *(const float4*)&As[kk][ty*4];
            float4 b = *(const float4*)&Ws[kk][tx*4];
            acc[0][0] += a.x*b.x; acc[0][1] += a.x*b.y; acc[0][2] += a.x*b.z; acc[0][3] += a.x*b.w;
            acc[1][0] += a.y*b.x; acc[1][1] += a.y*b.y; acc[1][2] += a.y*b.z; acc[1][3] += a.y*b.w;
            acc[2][0] += a.z*b.x; acc[2][1] += a.z*b.y; acc[2][2] += a.z*b.z; acc[2][3] += a.z*b.w;
            acc[3][0] += a.w*b.x; acc[3][1] += a.w*b.y; acc[3][2] += a.w*b.z; acc[3][3] += a.w*b.w;
        }
    }

    #pragma unroll
    for (int rr = 0; rr < 4; ++rr) {
        const int r = row0 + ty*4 + rr;
        const float s = ROWSCALE ? rscale[r] : 1.0f;
        float o[4];
        #pragma unroll
        for (int cc = 0; cc < 4; ++cc) {
            float v = acc[rr][cc] * s;
            if (BIAS) v += bias[col0 + tx*4 + cc];
            if (RELU) v = fmaxf(v, 0.0f);
            o[cc] = v;
        }
        float4 ov = make_float4(o[0], o[1], o[2], o[3]);
        *(float4*)&C[(size_t)r * NO + col0 + tx*4] = ov;
    }
}

// ======================================================================
// Row squared-norms: one wave per row
// ======================================================================
__global__ __launch_bounds__(256)
void sq_kernel(const float* __restrict__ h0, float* __restrict__ sq)
{
    const int wid = threadIdx.x >> 6, lane = threadIdx.x & 63;
    const int row = blockIdx.x * 4 + wid;
    float4 v = *(const float4*)&h0[(size_t)row * DIM + lane * 4];
    float s = v.x*v.x + v.y*v.y + v.z*v.z + v.w*v.w;
    #pragma unroll
    for (int o = 32; o > 0; o >>= 1) s += __shfl_down(s, o);
    if (lane == 0) sq[row] = s;
}

// ======================================================================
// kNN top-16: exact fp32. 64 rows/block, 64-col tiles, K chunked by 128.
// ======================================================================
__device__ __forceinline__ void topk_insert(float (&dv)[16], int (&iv)[16], float d, int j)
{
    // compile-time-indexed insertion network: stays in registers
    #pragma unroll
    for (int p = 15; p >= 0; --p) {
        if (d < dv[p]) {
            if (p < 15) { dv[p+1] = dv[p]; iv[p+1] = iv[p]; }
            dv[p] = d; iv[p] = j;
        }
    }
}

__device__ __forceinline__ void dot4_accum(float (&accr)[4], const float4 a,
                                           const float4 b0, const float4 b1,
                                           const float4 b2, const float4 b3)
{
    accr[0] += a.x*b0.x + a.y*b1.x + a.z*b2.x + a.w*b3.x;
    accr[1] += a.x*b0.y + a.y*b1.y + a.z*b2.y + a.w*b3.y;
    accr[2] += a.x*b0.z + a.y*b1.z + a.z*b2.z + a.w*b3.z;
    accr[3] += a.x*b0.w + a.y*b1.w + a.z*b2.w + a.w*b3.w;
}

__global__ __launch_bounds__(256, 2)
void knn_topk(const float* __restrict__ h0, const float* __restrict__ sq,
              int* __restrict__ nbr)
{
    __shared__ __align__(16) float Asl[64][132];   // A chunk [row][k], 33.8 KB
    __shared__ __align__(16) float Bsl[128][68];   // B chunk [k][col], 34.8 KB

    const int tid = threadIdx.x;
    const int cg = tid & 15;       // col group (4 cols)
    const int rg = tid >> 4;       // row group (4 rows)
    const int R0 = blockIdx.x * 64;

    float sqr[4];
    #pragma unroll
    for (int rr = 0; rr < 4; ++rr) sqr[rr] = sq[R0 + rg*4 + rr];

    float dl[4][16]; int il[4][16];
    #pragma unroll
    for (int rr = 0; rr < 4; ++rr)
        #pragma unroll
        for (int s = 0; s < 16; ++s) { dl[rr][s] = 3e38f; il[rr][s] = 0x7fffffff; }

    for (int jt = 0; jt < NN/64; ++jt) {
        const int J0 = jt * 64;
        float acc[4][4] = {};

        #pragma unroll
        for (int ch = 0; ch < 2; ++ch) {
            __syncthreads();
            // A chunk: rows R0..R0+63, k in [ch*128, ch*128+128). Coalesced.
            #pragma unroll
            for (int it = 0; it < 8; ++it) {
                int lin = tid + it * 256;
                int row = lin >> 5, kq = lin & 31;
                float4 v = *(const float4*)&h0[(size_t)(R0+row)*DIM + ch*128 + kq*4];
                *(float4*)&Asl[row][kq*4] = v;
            }
            // B chunk: rows J0..J0+63 (= cols of d2), transposed into [k][col]
            #pragma unroll
            for (int it = 0; it < 8; ++it) {
                int lin = tid + it * 256;
                int col = lin & 63, kq = lin >> 6;
                float4 v = *(const float4*)&h0[(size_t)(J0+col)*DIM + ch*128 + kq*4];
                Bsl[kq*4+0][col] = v.x; Bsl[kq*4+1][col] = v.y;
                Bsl[kq*4+2][col] = v.z; Bsl[kq*4+3][col] = v.w;
            }
            __syncthreads();

            #pragma unroll 2
            for (int k = 0; k < 128; k += 4) {
                float4 b0 = *(const float4*)&Bsl[k+0][cg*4];
                float4 b1 = *(const float4*)&Bsl[k+1][cg*4];
                float4 b2 = *(const float4*)&Bsl[k+2][cg*4];
                float4 b3 = *(const float4*)&Bsl[k+3][cg*4];
                float4 a0 = *(const float4*)&Asl[rg*4+0][k];
                float4 a1 = *(const float4*)&Asl[rg*4+1][k];
                float4 a2 = *(const float4*)&Asl[rg*4+2][k];
                float4 a3 = *(const float4*)&Asl[rg*4+3][k];
                dot4_accum(acc[0], a0, b0, b1, b2, b3);
                dot4_accum(acc[1], a1, b0, b1, b2, b3);
                dot4_accum(acc[2], a2, b0, b1, b2, b3);
                dot4_accum(acc[3], a3, b0, b1, b2, b3);
            }
        }

        float sqc[4];
        #pragma unroll
        for (int cc = 0; cc < 4; ++cc) sqc[cc] = sq[J0 + cg*4 + cc];

        #pragma unroll
        for (int cc = 0; cc < 4; ++cc) {
            const int j = J0 + cg*4 + cc;
            #pragma unroll
            for (int rr = 0; rr < 4; ++rr) {
                const int ig = R0 + rg*4 + rr;
                const float d = (sqr[rr] + sqc[cc]) - 2.0f * acc[rr][cc];
                if (j != ig && d < dl[rr][15]) topk_insert(dl[rr], il[rr], d, j);
            }
        }
    }

    // ---- merge: 4 passes of 16 rows; 16 lists x 16 entries per row ----
    float* cd = (float*)&Asl[0][0];   // [16][257] floats (4112 <= 8448)
    int*   ci = (int*)&Bsl[0][0];     // [16][257] ints  (4112 <= 8704)
    for (int pass = 0; pass < 4; ++pass) {
        __syncthreads();
        if ((rg >> 2) == pass) {
            const int rbase = (rg & 3) * 4;
            #pragma unroll
            for (int rr = 0; rr < 4; ++rr)
                #pragma unroll
                for (int s = 0; s < 16; ++s) {
                    const int lrp = rbase + rr;
                    cd[lrp*257 + cg*16 + s] = dl[rr][s];
                    ci[lrp*257 + cg*16 + s] = il[rr][s];
                }
        }
        __syncthreads();
        if (tid < 64) {
            const int sub = tid & 3;       // 4 lanes cooperate per row
            const int lrp = tid >> 2;
            const int grow = R0 + pass*16 + lrp;
            for (int t = 0; t < 16; ++t) {
                float bd = 3e38f; int bi = 0x7fffffff; int bs = 0;
                for (int s0 = 0; s0 < 64; ++s0) {
                    const int s = sub*64 + s0;
                    const float dv = cd[lrp*257 + s];
                    const int   iv = ci[lrp*257 + s];
                    if (dv < bd || (dv == bd && iv < bi)) { bd = dv; bi = iv; bs = s; }
                }
                #pragma unroll
                for (int off = 1; off < 4; off <<= 1) {
                    const float od = __shfl_xor(bd, off);
                    const int   oi = __shfl_xor(bi, off);
                    const int   os = __shfl_xor(bs, off);
                    if (od < bd || (od == bd && oi < bi)) { bd = od; bi = oi; bs = os; }
                }
                cd[lrp*257 + bs] = 3e38f;            // all 4 lanes, same addr/value
                if (sub == 0) nbr[(size_t)grow*KNN + t] = bi;
            }
        }
    }
}

// ======================================================================
// Graph build
// ======================================================================
__global__ void count_k(const int* __restrict__ nbr, int* __restrict__ indeg)
{
    const int e = blockIdx.x * 256 + threadIdx.x;
    atomicAdd(&indeg[nbr[e]], 1);
}

__global__ __launch_bounds__(1024)
void scan_k(const int* __restrict__ indeg, int* __restrict__ offs)
{
    __shared__ int part[1024];
    const int t = threadIdx.x;
    int pre[16]; int s = 0;
    #pragma unroll
    for (int j = 0; j < 16; ++j) { pre[j] = s; s += indeg[t*16 + j]; }
    part[t] = s;
    __syncthreads();
    for (int d = 1; d < 1024; d <<= 1) {
        int v = (t >= d) ? part[t - d] : 0;
        __syncthreads();
        part[t] += v;
        __syncthreads();
    }
    const int base = (t > 0) ? part[t-1] : 0;
    #pragma unroll
    for (int j = 0; j < 16; ++j) offs[t*16 + j] = base + pre[j];
}

__global__ void fill_k(const int* __restrict__ nbr, const int* __restrict__ offs,
                       int* __restrict__ cursor, int* __restrict__ rev)
{
    const int e = blockIdx.x * 256 + threadIdx.x;
    const int v = nbr[e];
    const int i = e >> 4;
    const int p = atomicAdd(&cursor[v], 1);
    rev[offs[v] + p] = i;
}

__global__ void dinv_k(const int* __restrict__ indeg, float* __restrict__ dinv)
{
    const int v = blockIdx.x * 256 + threadIdx.x;
    dinv[v] = rsqrtf((float)(indeg[v] + KNN + 1));
}

// ======================================================================
// GCN aggregation (gather): out[v] = relu(dinv[v]*(sum m'[u]) + b)
// m' rows already scaled by dinv[u] in the GEMM epilogue.
// ======================================================================
__global__ __launch_bounds__(256)
void gather_k(const float* __restrict__ m, const int* __restrict__ nbr,
              const int* __restrict__ rev, const int* __restrict__ offs,
              const int* __restrict__ indeg, const float* __restrict__ dinv,
              const float* __restrict__ bias, float* __restrict__ outp)
{
    const int v = blockIdx.x;
    const int f = threadIdx.x;
    float acc = m[(size_t)v*DIM + f];                  // self loop
    const int* nb = &nbr[(size_t)v*KNN];
    #pragma unroll
    for (int t = 0; t < KNN; ++t) {
        const int u = nb[t];
        acc += m[(size_t)u*DIM + f];
    }
    const int o = offs[v], n = indeg[v];
    for (int t = 0; t < n; ++t) {
        const int u = rev[o + t];
        acc += m[(size_t)u*DIM + f];
    }
    const float r = dinv[v] * acc + bias[f];
    outp[(size_t)v*DIM + f] = fmaxf(r, 0.0f);
}

// ======================================================================
// FC2: pred[i,c] = hid[i,:] . Wfc2[c,:] + b[c]
// ======================================================================
__global__ void fc2_k(const float* __restrict__ hid, const float* __restrict__ W,
                      const float* __restrict__ b, float* __restrict__ out)
{
    const int g = blockIdx.x * 256 + threadIdx.x;
    if (g >= NN * 10) return;
    const int i = g / 10;
    const int c = g - i * 10;
    float acc = 0.0f;
    #pragma unroll 4
    for (int k = 0; k < 128; ++k) acc += hid[(size_t)i*128 + k] * W[c*128 + k];
    out[g] = acc + b[c];
}

// ======================================================================
extern "C" void kernel_launch(void* const* d_in, const int* in_sizes, int n_in,
                              void* d_out, int out_size, void* d_ws, size_t ws_size,
                              hipStream_t stream)
{
    const float* x     = (const float*)d_in[0];
    const float* Wpre  = (const float*)d_in[1];
    const float* bpre  = (const float*)d_in[2];
    const float* Wconv = (const float*)d_in[3];   // [2][256][256]
    const float* bconv = (const float*)d_in[4];   // [2][256]
    const float* Wfc1  = (const float*)d_in[5];   // [128][256]
    const float* bfc1  = (const float*)d_in[6];
    const float* Wfc2  = (const float*)d_in[7];   // [10][128]
    const float* bfc2  = (const float*)d_in[8];
    float* out = (float*)d_out;

    float* ws    = (float*)d_ws;
    float* h0    = ws;                               // NN*DIM
    float* mbuf  = h0    + (size_t)NN*DIM;           // NN*DIM
    float* hfbuf = mbuf  + (size_t)NN*DIM;           // NN*DIM
    float* hid   = hfbuf + (size_t)NN*DIM;           // NN*128
    float* sqv   = hid   + (size_t)NN*128;           // NN
    float* dinv  = sqv   + NN;                       // NN
    int*   nbr   = (int*)(dinv + NN);                // NN*KNN
    int*   indeg = nbr   + (size_t)NN*KNN;           // NN
    int*   offs  = indeg + NN;                       // NN
    int*   cursor= offs  + NN;                       // NN
    int*   rev   = cursor+ NN;                       // NN*KNN

    hipMemsetAsync(indeg,  0, NN*sizeof(int), stream);
    hipMemsetAsync(cursor, 0, NN*sizeof(int), stream);

    // 1. h0 = relu(x @ Wpre^T + bpre)
    gemm_nt<true,true,false><<<dim3(DIM/64, NN/64), 256, 0, stream>>>(
        x, Wpre, bpre, nullptr, h0, NN, DIM, DIM);
    // 2. row squared norms
    sq_kernel<<<NN/4, 256, 0, stream>>>(h0, sqv);
    // 3. exact 16-NN
    knn_topk<<<NN/64, 256, 0, stream>>>(h0, sqv, nbr);
    // 4. graph build
    count_k<<<NN*KNN/256, 256, 0, stream>>>(nbr, indeg);
    scan_k<<<1, 1024, 0, stream>>>(indeg, offs);
    fill_k<<<NN*KNN/256, 256, 0, stream>>>(nbr, offs, cursor, rev);
    dinv_k<<<NN/256, 256, 0, stream>>>(indeg, dinv);
    // 5. GCN layer 1: m = (h0 @ Wc0^T) * dinv[row]; hf = relu(dinv*agg + b0)
    gemm_nt<false,false,true><<<dim3(DIM/64, NN/64), 256, 0, stream>>>(
        h0, Wconv, nullptr, dinv, mbuf, NN, DIM, DIM);
    gather_k<<<NN, 256, 0, stream>>>(mbuf, nbr, rev, offs, indeg, dinv, bconv, hfbuf);
    // 6. GCN layer 2 (m2 -> h0 slot, hf2 -> mbuf slot)
    gemm_nt<false,false,true><<<dim3(DIM/64, NN/64), 256, 0, stream>>>(
        hfbuf, Wconv + DIM*DIM, nullptr, dinv, h0, NN, DIM, DIM);
    gather_k<<<NN, 256, 0, stream>>>(h0, nbr, rev, offs, indeg, dinv, bconv + DIM, mbuf);
    // 7. FC1: hid = relu(hf2 @ Wfc1^T + b)
    gemm_nt<true,true,false><<<dim3(128/64, NN/64), 256, 0, stream>>>(
        mbuf, Wfc1, bfc1, nullptr, hid, NN, DIM, 128);
    // 8. FC2
    fc2_k<<<NN*10/256, 256, 0, stream>>>(hid, Wfc2, bfc2, out);
}

// Round 2
// 3628.856 us; speedup vs baseline: 1.8056x; 1.8056x over previous
//
#include <hip/hip_runtime.h>

#define NN   16384
#define DIM  256
#define KNN  16
#define SEG  4
#define JT_PER (NN / SEG / 128)   // 32 column tiles per segment

// ======================================================================
// Generic fp32 GEMM:  C[M,NO] = act( rowscale(A[M,K] @ W[NO,K]^T) + bias )
// BM=BN=64, TK=16, 256 threads, 4x4 micro-tile.
// ======================================================================
template<bool RELU, bool BIAS, bool ROWSCALE>
__global__ __launch_bounds__(256)
void gemm_nt(const float* __restrict__ A, const float* __restrict__ W,
             const float* __restrict__ bias, const float* __restrict__ rscale,
             float* __restrict__ C, int M, int K, int NO)
{
    __shared__ __align__(16) float As[16][68];
    __shared__ __align__(16) float Ws[16][68];
    const int tid = threadIdx.x;
    const int tx = tid & 15, ty = tid >> 4;
    const int row0 = blockIdx.y * 64, col0 = blockIdx.x * 64;
    const int lr = tid >> 2;          // 0..63
    const int lk = (tid & 3) * 4;     // 0,4,8,12

    float acc[4][4] = {};

    for (int k0 = 0; k0 < K; k0 += 16) {
        float4 av = *(const float4*)&A[(size_t)(row0 + lr) * K + k0 + lk];
        float4 wv = *(const float4*)&W[(size_t)(col0 + lr) * K + k0 + lk];
        __syncthreads();
        As[lk+0][lr] = av.x; As[lk+1][lr] = av.y; As[lk+2][lr] = av.z; As[lk+3][lr] = av.w;
        Ws[lk+0][lr] = wv.x; Ws[lk+1][lr] = wv.y; Ws[lk+2][lr] = wv.z; Ws[lk+3][lr] = wv.w;
        __syncthreads();
        #pragma unroll
        for (int kk = 0; kk < 16; ++kk) {
            float4 a = *(const float4*)&As[kk][ty*4];
            float4 b = *(const float4*)&Ws[kk][tx*4];
            acc[0][0] += a.x*b.x; acc[0][1] += a.x*b.y; acc[0][2] += a.x*b.z; acc[0][3] += a.x*b.w;
            acc[1][0] += a.y*b.x; acc[1][1] += a.y*b.y; acc[1][2] += a.y*b.z; acc[1][3] += a.y*b.w;
            acc[2][0] += a.z*b.x; acc[2][1] += a.z*b.y; acc[2][2] += a.z*b.z; acc[2][3] += a.z*b.w;
            acc[3][0] += a.w*b.x; acc[3][1] += a.w*b.y; acc[3][2] += a.w*b.z; acc[3][3] += a.w*b.w;
        }
    }

    #pragma unroll
    for (int rr = 0; rr < 4; ++rr) {
        const int r = row0 + ty*4 + rr;
        const float s = ROWSCALE ? rscale[r] : 1.0f;
        float o[4];
        #pragma unroll
        for (int cc = 0; cc < 4; ++cc) {
            float v = acc[rr][cc] * s;
            if (BIAS) v += bias[col0 + tx*4 + cc];
            if (RELU) v = fmaxf(v, 0.0f);
            o[cc] = v;
        }
        float4 ov = make_float4(o[0], o[1], o[2], o[3]);
        *(float4*)&C[(size_t)r * NO + col0 + tx*4] = ov;
    }
}

// ======================================================================
// Row squared-norms: one wave per row
// ======================================================================
__global__ __launch_bounds__(256)
void sq_kernel(const float* __restrict__ h0, float* __restrict__ sq)
{
    const int wid = threadIdx.x >> 6, lane = threadIdx.x & 63;
    const int row = blockIdx.x * 4 + wid;
    float4 v = *(const float4*)&h0[(size_t)row * DIM + lane * 4];
    float s = v.x*v.x + v.y*v.y + v.z*v.z + v.w*v.w;
    #pragma unroll
    for (int o = 32; o > 0; o >>= 1) s += __shfl_down(s, o);
    if (lane == 0) sq[row] = s;
}

// ======================================================================
// Register-resident top-16 insertion network (compile-time indexed)
// ======================================================================
__device__ __forceinline__ void topk_insert(float (&dv)[16], int (&iv)[16], float d, int j)
{
    #pragma unroll
    for (int p = 15; p >= 0; --p) {
        if (d < dv[p]) {
            if (p < 15) { dv[p+1] = dv[p]; iv[p+1] = iv[p]; }
            dv[p] = d; iv[p] = j;
        }
    }
}

// ======================================================================
// kNN: 128x128 distance tiles, 8x8 micro-tile, XOR-swizzled LDS.
// Grid: (SEG, NN/128). Each block covers 128 rows x 4096 cols and emits
// a sorted top-16 (d,idx) partial list per row into cand_d/cand_i.
// Per-tile the distance block is redistributed through LDS so each
// thread owns 1 row x 64-col half -> top-16 list lives in registers.
// ======================================================================
__global__ __launch_bounds__(256, 2)
void knn_topk(const float* __restrict__ h0, const float* __restrict__ sq,
              float* __restrict__ cand_d, int* __restrict__ cand_i)
{
    __shared__ float smem[16384];           // 64 KB: A[128][64] + B[128][64] / D[128][128]
    float* Asl = smem;
    float* Bsl = smem + 8192;

    const int tid = threadIdx.x;
    const int tx = tid & 15, ty = tid >> 4;
    const int R0 = blockIdx.y * 128;
    const int seg = blockIdx.x;
    const int sA = (ty & 7) << 2;           // fragment k-XOR (A rows)
    const int sB = (tx & 7) << 2;           // fragment k-XOR (B cols)

    // top-k ownership: 1 row x 64-col half per thread
    const int orow  = tid >> 1;             // 0..127
    const int ohalf = tid & 1;
    const int myrow = R0 + orow;
    const float osq = sq[myrow];
    const int swzr = (orow & 7) << 2;       // D-matrix row XOR

    float dl[16]; int il[16];
    #pragma unroll
    for (int e = 0; e < 16; ++e) { dl[e] = 3e38f; il[e] = 0x7fffffff; }

    for (int jt = 0; jt < JT_PER; ++jt) {
        const int C0 = seg * (NN / SEG) + jt * 128;
        float acc[8][8] = {};

        #pragma unroll 1
        for (int ch = 0; ch < 4; ++ch) {
            const int k0g = ch * 64;
            // stage A(128 rows x 64k) and B(128 cols x 64k), point-major, k XOR-swizzled
            float4 av[8], bv[8];
            #pragma unroll
            for (int it = 0; it < 8; ++it) {
                const int lin = tid + it * 256;
                const int row = lin >> 4, kq = lin & 15;
                av[it] = *(const float4*)&h0[(size_t)(R0 + row) * DIM + k0g + kq * 4];
                bv[it] = *(const float4*)&h0[(size_t)(C0 + row) * DIM + k0g + kq * 4];
            }
            __syncthreads();
            #pragma unroll
            for (int it = 0; it < 8; ++it) {
                const int lin = tid + it * 256;
                const int row = lin >> 4, kq = lin & 15;
                const int sw = ((row >> 2) & 7) << 2;
                *(float4*)&Asl[row * 64 + ((kq * 4) ^ sw)] = av[it];
                *(float4*)&Bsl[row * 64 + ((kq * 4) ^ sw)] = bv[it];
            }
            __syncthreads();

            #pragma unroll 2
            for (int k0 = 0; k0 < 64; k0 += 4) {
                const int ka = k0 ^ sA;
                const int kb = k0 ^ sB;
                float4 a[8], b[8];
                #pragma unroll
                for (int s = 0; s < 4; ++s) {
                    a[s]     = *(const float4*)&Asl[(ty*4 + s) * 64 + ka];
                    a[s + 4] = *(const float4*)&Asl[(64 + ty*4 + s) * 64 + ka];
                    b[s]     = *(const float4*)&Bsl[(tx*4 + s) * 64 + kb];
                    b[s + 4] = *(const float4*)&Bsl[(64 + tx*4 + s) * 64 + kb];
                }
                #pragma unroll
                for (int i = 0; i < 8; ++i)
                    #pragma unroll
                    for (int j = 0; j < 8; ++j) {
                        acc[i][j] = fmaf(a[i].x, b[j].x, acc[i][j]);
                        acc[i][j] = fmaf(a[i].y, b[j].y, acc[i][j]);
                        acc[i][j] = fmaf(a[i].z, b[j].z, acc[i][j]);
                        acc[i][j] = fmaf(a[i].w, b[j].w, acc[i][j]);
                    }
            }
        }

        // redistribute: dump 128x128 dot-products into D (XOR-swizzled), reuse smem
        __syncthreads();
        #pragma unroll
        for (int i = 0; i < 8; ++i) {
            const int row = (i < 4) ? (ty*4 + i) : (64 + ty*4 + (i - 4));
            const int swz = (row & 7) << 2;
            *(float4*)&smem[row * 128 + ((tx*4) ^ swz)] =
                make_float4(acc[i][0], acc[i][1], acc[i][2], acc[i][3]);
            *(float4*)&smem[row * 128 + ((64 + tx*4) ^ swz)] =
                make_float4(acc[i][4], acc[i][5], acc[i][6], acc[i][7]);
        }
        __syncthreads();

        // candidate phase: this thread's row x its 64-col half
        const int cbase = C0 + ohalf * 64;
        #pragma clang loop unroll(disable)
        for (int e = 0; e < 16; ++e) {
            const float4 dv4 = *(const float4*)&smem[orow * 128 + ((ohalf*64 + e*4) ^ swzr)];
            const float4 sv4 = *(const float4*)&sq[cbase + e*4];
            const int j0 = cbase + e*4;
            float d;
            d = (osq + sv4.x) - 2.0f * dv4.x;
            if (j0 + 0 != myrow && d < dl[15]) topk_insert(dl, il, d, j0 + 0);
            d = (osq + sv4.y) - 2.0f * dv4.y;
            if (j0 + 1 != myrow && d < dl[15]) topk_insert(dl, il, d, j0 + 1);
            d = (osq + sv4.z) - 2.0f * dv4.z;
            if (j0 + 2 != myrow && d < dl[15]) topk_insert(dl, il, d, j0 + 2);
            d = (osq + sv4.w) - 2.0f * dv4.w;
            if (j0 + 3 != myrow && d < dl[15]) topk_insert(dl, il, d, j0 + 3);
        }
        // next tile's staging barrier protects smem before overwrite
    }

    // block-level merge: 2 half-lists per row -> sorted 16 per row
    __syncthreads();
    #pragma unroll
    for (int e = 0; e < 16; ++e) {
        Asl[tid * 17 + e] = dl[e];
        ((int*)Bsl)[tid * 17 + e] = il[e];
    }
    __syncthreads();
    if (tid < 128) {
        const float* LA = &Asl[(2*tid) * 17];
        const float* LB = &Asl[(2*tid + 1) * 17];
        const int* IA = &((int*)Bsl)[(2*tid) * 17];
        const int* IB = &((int*)Bsl)[(2*tid + 1) * 17];
        int pa = 0, pb = 0;
        const size_t obase = ((size_t)seg * NN + R0 + tid) * 16;
        #pragma clang loop unroll(disable)
        for (int r = 0; r < 16; ++r) {
            const float da = LA[pa], db = LB[pb];
            const int ia = IA[pa], ib = IB[pb];
            const bool takeA = (da < db) || (da == db && ia < ib);
            cand_d[obase + r] = takeA ? da : db;
            cand_i[obase + r] = takeA ? ia : ib;
            if (takeA) ++pa; else ++pb;
        }
    }
}

// ======================================================================
// Final merge of SEG sorted 16-lists per row -> nbr[row][16]
// 4 lanes per row, 64 rows per block.
// ======================================================================
__global__ __launch_bounds__(256)
void merge4_k(const float* __restrict__ cand_d, const int* __restrict__ cand_i,
              int* __restrict__ nbr)
{
    const int tid = threadIdx.x;
    const int row = blockIdx.x * 64 + (tid >> 2);
    const int l = tid & 3;                  // segment lane
    int head = 0;
    for (int round = 0; round < 16; ++round) {
        const size_t base = ((size_t)l * NN + row) * 16;
        float md = (head < 16) ? cand_d[base + head] : 3e38f;
        int   mi = (head < 16) ? cand_i[base + head] : 0x7fffffff;
        int   ml = l;
        #pragma unroll
        for (int off = 1; off < 4; off <<= 1) {
            const float od = __shfl_xor(md, off);
            const int   oi = __shfl_xor(mi, off);
            const int   ol = __shfl_xor(ml, off);
            if (od < md || (od == md && oi < mi)) { md = od; mi = oi; ml = ol; }
        }
        if (ml == l) ++head;
        if (l == 0) nbr[(size_t)row * KNN + round] = mi;
    }
}

// ======================================================================
// Graph build
// ======================================================================
__global__ void count_k(const int* __restrict__ nbr, int* __restrict__ indeg)
{
    const int e = blockIdx.x * 256 + threadIdx.x;
    atomicAdd(&indeg[nbr[e]], 1);
}

__global__ __launch_bounds__(1024)
void scan_k(const int* __restrict__ indeg, int* __restrict__ offs)
{
    __shared__ int part[1024];
    const int t = threadIdx.x;
    int pre[16]; int s = 0;
    #pragma unroll
    for (int j = 0; j < 16; ++j) { pre[j] = s; s += indeg[t*16 + j]; }
    part[t] = s;
    __syncthreads();
    for (int d = 1; d < 1024; d <<= 1) {
        int v = (t >= d) ? part[t - d] : 0;
        __syncthreads();
        part[t] += v;
        __syncthreads();
    }
    const int base = (t > 0) ? part[t-1] : 0;
    #pragma unroll
    for (int j = 0; j < 16; ++j) offs[t*16 + j] = base + pre[j];
}

__global__ void fill_k(const int* __restrict__ nbr, const int* __restrict__ offs,
                       int* __restrict__ cursor, int* __restrict__ rev)
{
    const int e = blockIdx.x * 256 + threadIdx.x;
    const int v = nbr[e];
    const int i = e >> 4;
    const int p = atomicAdd(&cursor[v], 1);
    rev[offs[v] + p] = i;
}

__global__ void dinv_k(const int* __restrict__ indeg, float* __restrict__ dinv)
{
    const int v = blockIdx.x * 256 + threadIdx.x;
    dinv[v] = rsqrtf((float)(indeg[v] + KNN + 1));
}

// ======================================================================
// GCN aggregation (gather): out[v] = relu(dinv[v]*(sum m'[u]) + b)
// m' rows already scaled by dinv[u] in the GEMM epilogue.
// ======================================================================
__global__ __launch_bounds__(256)
void gather_k(const float* __restrict__ m, const int* __restrict__ nbr,
              const int* __restrict__ rev, const int* __restrict__ offs,
              const int* __restrict__ indeg, const float* __restrict__ dinv,
              const float* __restrict__ bias, float* __restrict__ outp)
{
    const int v = blockIdx.x;
    const int f = threadIdx.x;
    float acc = m[(size_t)v*DIM + f];                  // self loop
    const int* nb = &nbr[(size_t)v*KNN];
    #pragma unroll
    for (int t = 0; t < KNN; ++t) {
        const int u = nb[t];
        acc += m[(size_t)u*DIM + f];
    }
    const int o = offs[v], n = indeg[v];
    for (int t = 0; t < n; ++t) {
        const int u = rev[o + t];
        acc += m[(size_t)u*DIM + f];
    }
    const float r = dinv[v] * acc + bias[f];
    outp[(size_t)v*DIM + f] = fmaxf(r, 0.0f);
}

// ======================================================================
// FC2: pred[i,c] = hid[i,:] . Wfc2[c,:] + b[c]
// ======================================================================
__global__ void fc2_k(const float* __restrict__ hid, const float* __restrict__ W,
                      const float* __restrict__ b, float* __restrict__ out)
{
    const int g = blockIdx.x * 256 + threadIdx.x;
    if (g >= NN * 10) return;
    const int i = g / 10;
    const int c = g - i * 10;
    float acc = 0.0f;
    #pragma unroll 4
    for (int k = 0; k < 128; ++k) acc += hid[(size_t)i*128 + k] * W[c*128 + k];
    out[g] = acc + b[c];
}

// ======================================================================
extern "C" void kernel_launch(void* const* d_in, const int* in_sizes, int n_in,
                              void* d_out, int out_size, void* d_ws, size_t ws_size,
                              hipStream_t stream)
{
    const float* x     = (const float*)d_in[0];
    const float* Wpre  = (const float*)d_in[1];
    const float* bpre  = (const float*)d_in[2];
    const float* Wconv = (const float*)d_in[3];   // [2][256][256]
    const float* bconv = (const float*)d_in[4];   // [2][256]
    const float* Wfc1  = (const float*)d_in[5];   // [128][256]
    const float* bfc1  = (const float*)d_in[6];
    const float* Wfc2  = (const float*)d_in[7];   // [10][128]
    const float* bfc2  = (const float*)d_in[8];
    float* out = (float*)d_out;

    float* ws    = (float*)d_ws;
    float* h0    = ws;                               // NN*DIM
    float* mbuf  = h0    + (size_t)NN*DIM;           // NN*DIM
    float* hfbuf = mbuf  + (size_t)NN*DIM;           // NN*DIM
    float* hid   = hfbuf + (size_t)NN*DIM;           // NN*128
    float* sqv   = hid   + (size_t)NN*128;           // NN
    float* dinv  = sqv   + NN;                       // NN
    int*   nbr   = (int*)(dinv + NN);                // NN*KNN
    int*   indeg = nbr   + (size_t)NN*KNN;           // NN
    int*   offs  = indeg + NN;                       // NN
    int*   cursor= offs  + NN;                       // NN
    int*   rev   = cursor+ NN;                       // NN*KNN
    float* cand_d= (float*)(rev + (size_t)NN*KNN);   // SEG*NN*16
    int*   cand_i= (int*)(cand_d + (size_t)SEG*NN*16); // SEG*NN*16

    hipMemsetAsync(indeg,  0, NN*sizeof(int), stream);
    hipMemsetAsync(cursor, 0, NN*sizeof(int), stream);

    // 1. h0 = relu(x @ Wpre^T + bpre)
    gemm_nt<true,true,false><<<dim3(DIM/64, NN/64), 256, 0, stream>>>(
        x, Wpre, bpre, nullptr, h0, NN, DIM, DIM);
    // 2. row squared norms
    sq_kernel<<<NN/4, 256, 0, stream>>>(h0, sqv);
    // 3. exact 16-NN (segmented) + merge
    knn_topk<<<dim3(SEG, NN/128), 256, 0, stream>>>(h0, sqv, cand_d, cand_i);
    merge4_k<<<NN/64, 256, 0, stream>>>(cand_d, cand_i, nbr);
    // 4. graph build
    count_k<<<NN*KNN/256, 256, 0, stream>>>(nbr, indeg);
    scan_k<<<1, 1024, 0, stream>>>(indeg, offs);
    fill_k<<<NN*KNN/256, 256, 0, stream>>>(nbr, offs, cursor, rev);
    dinv_k<<<NN/256, 256, 0, stream>>>(indeg, dinv);
    // 5. GCN layer 1: m = (h0 @ Wc0^T) * dinv[row]; hf = relu(dinv*agg + b0)
    gemm_nt<false,false,true><<<dim3(DIM/64, NN/64), 256, 0, stream>>>(
        h0, Wconv, nullptr, dinv, mbuf, NN, DIM, DIM);
    gather_k<<<NN, 256, 0, stream>>>(mbuf, nbr, rev, offs, indeg, dinv, bconv, hfbuf);
    // 6. GCN layer 2 (m2 -> h0 slot, hf2 -> mbuf slot)
    gemm_nt<false,false,true><<<dim3(DIM/64, NN/64), 256, 0, stream>>>(
        hfbuf, Wconv + DIM*DIM, nullptr, dinv, h0, NN, DIM, DIM);
    gather_k<<<NN, 256, 0, stream>>>(h0, nbr, rev, offs, indeg, dinv, bconv + DIM, mbuf);
    // 7. FC1: hid = relu(hf2 @ Wfc1^T + b)
    gemm_nt<true,true,false><<<dim3(128/64, NN/64), 256, 0, stream>>>(
        mbuf, Wfc1, bfc1, nullptr, hid, NN, DIM, 128);
    // 8. FC2
    fc2_k<<<NN*10/256, 256, 0, stream>>>(hid, Wfc2, bfc2, out);
}

// Round 3
// 2898.414 us; speedup vs baseline: 2.2606x; 1.2520x over previous
//
#include <hip/hip_runtime.h>

#define NN   16384
#define DIM  256
#define KNN  16
#define SEG  4
#define JT_PER (NN / SEG / 128)   // 32 column tiles per segment

// ======================================================================
// async global->LDS 16B helper (linear LDS dest, per-lane global source)
// ======================================================================
__device__ __forceinline__ void gload_lds16(const float* g, float* l)
{
    __builtin_amdgcn_global_load_lds(
        (const __attribute__((address_space(1))) unsigned int*)g,
        (__attribute__((address_space(3))) unsigned int*)l, 16, 0, 0);
}

// ======================================================================
// Generic fp32 GEMM:  C[M,NO] = act( rowscale(A[M,K] @ W[NO,K]^T) + bias )
// BM=BN=64, TK=16, 256 threads, 4x4 micro-tile.
// ======================================================================
template<bool RELU, bool BIAS, bool ROWSCALE>
__global__ __launch_bounds__(256)
void gemm_nt(const float* __restrict__ A, const float* __restrict__ W,
             const float* __restrict__ bias, const float* __restrict__ rscale,
             float* __restrict__ C, int M, int K, int NO)
{
    __shared__ __align__(16) float As[16][68];
    __shared__ __align__(16) float Ws[16][68];
    const int tid = threadIdx.x;
    const int tx = tid & 15, ty = tid >> 4;
    const int row0 = blockIdx.y * 64, col0 = blockIdx.x * 64;
    const int lr = tid >> 2;          // 0..63
    const int lk = (tid & 3) * 4;     // 0,4,8,12

    float acc[4][4] = {};

    for (int k0 = 0; k0 < K; k0 += 16) {
        float4 av = *(const float4*)&A[(size_t)(row0 + lr) * K + k0 + lk];
        float4 wv = *(const float4*)&W[(size_t)(col0 + lr) * K + k0 + lk];
        __syncthreads();
        As[lk+0][lr] = av.x; As[lk+1][lr] = av.y; As[lk+2][lr] = av.z; As[lk+3][lr] = av.w;
        Ws[lk+0][lr] = wv.x; Ws[lk+1][lr] = wv.y; Ws[lk+2][lr] = wv.z; Ws[lk+3][lr] = wv.w;
        __syncthreads();
        #pragma unroll
        for (int kk = 0; kk < 16; ++kk) {
            float4 a = *(const float4*)&As[kk][ty*4];
            float4 b = *(const float4*)&Ws[kk][tx*4];
            acc[0][0] += a.x*b.x; acc[0][1] += a.x*b.y; acc[0][2] += a.x*b.z; acc[0][3] += a.x*b.w;
            acc[1][0] += a.y*b.x; acc[1][1] += a.y*b.y; acc[1][2] += a.y*b.z; acc[1][3] += a.y*b.w;
            acc[2][0] += a.z*b.x; acc[2][1] += a.z*b.y; acc[2][2] += a.z*b.z; acc[2][3] += a.z*b.w;
            acc[3][0] += a.w*b.x; acc[3][1] += a.w*b.y; acc[3][2] += a.w*b.z; acc[3][3] += a.w*b.w;
        }
    }

    #pragma unroll
    for (int rr = 0; rr < 4; ++rr) {
        const int r = row0 + ty*4 + rr;
        const float s = ROWSCALE ? rscale[r] : 1.0f;
        float o[4];
        #pragma unroll
        for (int cc = 0; cc < 4; ++cc) {
            float v = acc[rr][cc] * s;
            if (BIAS) v += bias[col0 + tx*4 + cc];
            if (RELU) v = fmaxf(v, 0.0f);
            o[cc] = v;
        }
        float4 ov = make_float4(o[0], o[1], o[2], o[3]);
        *(float4*)&C[(size_t)r * NO + col0 + tx*4] = ov;
    }
}

// ======================================================================
// Row squared-norms: one wave per row
// ======================================================================
__global__ __launch_bounds__(256)
void sq_kernel(const float* __restrict__ h0, float* __restrict__ sq)
{
    const int wid = threadIdx.x >> 6, lane = threadIdx.x & 63;
    const int row = blockIdx.x * 4 + wid;
    float4 v = *(const float4*)&h0[(size_t)row * DIM + lane * 4];
    float s = v.x*v.x + v.y*v.y + v.z*v.z + v.w*v.w;
    #pragma unroll
    for (int o = 32; o > 0; o >>= 1) s += __shfl_down(s, o);
    if (lane == 0) sq[row] = s;
}

// ======================================================================
// Register-resident top-16 insertion network (compile-time indexed)
// ======================================================================
__device__ __forceinline__ void topk_insert(float (&dv)[16], int (&iv)[16], float d, int j)
{
    #pragma unroll
    for (int p = 15; p >= 0; --p) {
        if (d < dv[p]) {
            if (p < 15) { dv[p+1] = dv[p]; iv[p+1] = iv[p]; }
            dv[p] = d; iv[p] = j;
        }
    }
}

// ======================================================================
// kNN: 128x128 distance tiles, 8x8 micro-tile.
// A/B staged via global_load_lds (linear LDS dest, source pre-swizzled so
// the LDS layout is k-XOR-swizzled for conflict-free fragment reads).
// D redistribution: stride 132 + rotation swizzle (<=2-way conflicts).
// Top-16 list per (row, 64-col half) lives entirely in registers.
// ======================================================================
__global__ __launch_bounds__(256, 1)
void knn_topk(const float* __restrict__ h0, const float* __restrict__ sq,
              float* __restrict__ cand_d, int* __restrict__ cand_i)
{
    __shared__ __align__(16) float smem[16896];   // 67.6 KB: A[128][64]+B[128][64] / D[128][132]
    float* Asl = smem;
    float* Bsl = smem + 8192;

    const int tid = threadIdx.x;
    const int tx = tid & 15, ty = tid >> 4;
    const int R0 = blockIdx.y * 128;
    const int seg = blockIdx.x;
    const int sA = (ty & 7) << 2;           // fragment k-XOR (A rows)
    const int sB = (tx & 7) << 2;           // fragment k-XOR (B cols)

    // top-k ownership: 1 row x 64-col half per thread
    const int orow  = tid >> 1;             // 0..127
    const int ohalf = tid & 1;
    const int myrow = R0 + orow;
    const float osq = sq[myrow];

    float dl[16]; int il[16];
    #pragma unroll
    for (int e = 0; e < 16; ++e) { dl[e] = 3e38f; il[e] = 0x7fffffff; }

    for (int jt = 0; jt < JT_PER; ++jt) {
        const int C0 = seg * (NN / SEG) + jt * 128;
        float acc[8][8] = {};

        #pragma unroll 1
        for (int ch = 0; ch < 4; ++ch) {
            const int k0g = ch * 64;
            __syncthreads();   // protect smem from prior-phase readers
            // stage A(128 rows x 64k) and B(128 cols x 64k).
            // LDS dest linear in lane; global source k-slot pre-swizzled so
            // LDS slot f of row r holds element k = f ^ ((r>>2)&7) group.
            #pragma unroll
            for (int it = 0; it < 8; ++it) {
                const int lin = tid + it * 256;
                const int row = lin >> 4;          // 0..127 (wave-uniform 4-row chunk)
                const int f   = lin & 15;          // float4 slot
                const int kq  = f ^ ((row >> 2) & 7);
                gload_lds16(&h0[(size_t)(R0 + row) * DIM + k0g + kq * 4],
                            &Asl[row * 64 + f * 4]);
                gload_lds16(&h0[(size_t)(C0 + row) * DIM + k0g + kq * 4],
                            &Bsl[row * 64 + f * 4]);
            }
            __syncthreads();   // drains vmcnt(0) before barrier

            #pragma unroll 2
            for (int k0 = 0; k0 < 64; k0 += 4) {
                const int ka = k0 ^ sA;
                const int kb = k0 ^ sB;
                float4 a[8], b[8];
                #pragma unroll
                for (int s = 0; s < 4; ++s) {
                    a[s]     = *(const float4*)&Asl[(ty*4 + s) * 64 + ka];
                    a[s + 4] = *(const float4*)&Asl[(64 + ty*4 + s) * 64 + ka];
                    b[s]     = *(const float4*)&Bsl[(tx*4 + s) * 64 + kb];
                    b[s + 4] = *(const float4*)&Bsl[(64 + tx*4 + s) * 64 + kb];
                }
                #pragma unroll
                for (int i = 0; i < 8; ++i)
                    #pragma unroll
                    for (int j = 0; j < 8; ++j) {
                        acc[i][j] = fmaf(a[i].x, b[j].x, acc[i][j]);
                        acc[i][j] = fmaf(a[i].y, b[j].y, acc[i][j]);
                        acc[i][j] = fmaf(a[i].z, b[j].z, acc[i][j]);
                        acc[i][j] = fmaf(a[i].w, b[j].w, acc[i][j]);
                    }
            }
        }

        // redistribute: dump 128x128 dots into D[128][132], rotation-swizzled
        __syncthreads();
        #pragma unroll
        for (int i = 0; i < 8; ++i) {
            const int row = (i < 4) ? (ty*4 + i) : (64 + ty*4 + (i - 4));
            const int p = (tx + row) & 15;
            float* Drow = &smem[row * 132];
            *(float4*)&Drow[4 * p] =
                make_float4(acc[i][0], acc[i][1], acc[i][2], acc[i][3]);
            *(float4*)&Drow[4 * (16 + p)] =
                make_float4(acc[i][4], acc[i][5], acc[i][6], acc[i][7]);
        }
        __syncthreads();

        // candidate phase: this thread's row x its 64-col half
        const int cbase = C0 + ohalf * 64;
        const float* Drow = &smem[orow * 132 + ohalf * 64];
        #pragma clang loop unroll(disable)
        for (int e = 0; e < 16; ++e) {
            const float4 dv4 = *(const float4*)&Drow[4 * ((e + orow) & 15)];
            const float4 sv4 = *(const float4*)&sq[cbase + e*4];
            const int j0 = cbase + e*4;
            float d;
            d = (osq + sv4.x) - 2.0f * dv4.x;
            if (j0 + 0 != myrow && d < dl[15]) topk_insert(dl, il, d, j0 + 0);
            d = (osq + sv4.y) - 2.0f * dv4.y;
            if (j0 + 1 != myrow && d < dl[15]) topk_insert(dl, il, d, j0 + 1);
            d = (osq + sv4.z) - 2.0f * dv4.z;
            if (j0 + 2 != myrow && d < dl[15]) topk_insert(dl, il, d, j0 + 2);
            d = (osq + sv4.w) - 2.0f * dv4.w;
            if (j0 + 3 != myrow && d < dl[15]) topk_insert(dl, il, d, j0 + 3);
        }
    }

    // block-level merge: 2 half-lists per row -> sorted 16 per row
    __syncthreads();
    #pragma unroll
    for (int e = 0; e < 16; ++e) {
        Asl[tid * 17 + e] = dl[e];
        ((int*)Bsl)[tid * 17 + e] = il[e];
    }
    __syncthreads();
    if (tid < 128) {
        const float* LA = &Asl[(2*tid) * 17];
        const float* LB = &Asl[(2*tid + 1) * 17];
        const int* IA = &((int*)Bsl)[(2*tid) * 17];
        const int* IB = &((int*)Bsl)[(2*tid + 1) * 17];
        int pa = 0, pb = 0;
        const size_t obase = ((size_t)seg * NN + R0 + tid) * 16;
        #pragma clang loop unroll(disable)
        for (int r = 0; r < 16; ++r) {
            const float da = LA[pa], db = LB[pb];
            const int ia = IA[pa], ib = IB[pb];
            const bool takeA = (da < db) || (da == db && ia < ib);
            cand_d[obase + r] = takeA ? da : db;
            cand_i[obase + r] = takeA ? ia : ib;
            if (takeA) ++pa; else ++pb;
        }
    }
}

// ======================================================================
// Final merge of SEG sorted 16-lists per row -> nbr[row][16]
// ======================================================================
__global__ __launch_bounds__(256)
void merge4_k(const float* __restrict__ cand_d, const int* __restrict__ cand_i,
              int* __restrict__ nbr)
{
    const int tid = threadIdx.x;
    const int row = blockIdx.x * 64 + (tid >> 2);
    const int l = tid & 3;                  // segment lane
    int head = 0;
    for (int round = 0; round < 16; ++round) {
        const size_t base = ((size_t)l * NN + row) * 16;
        float md = (head < 16) ? cand_d[base + head] : 3e38f;
        int   mi = (head < 16) ? cand_i[base + head] : 0x7fffffff;
        int   ml = l;
        #pragma unroll
        for (int off = 1; off < 4; off <<= 1) {
            const float od = __shfl_xor(md, off);
            const int   oi = __shfl_xor(mi, off);
            const int   ol = __shfl_xor(ml, off);
            if (od < md || (od == md && oi < mi)) { md = od; mi = oi; ml = ol; }
        }
        if (ml == l) ++head;
        if (l == 0) nbr[(size_t)row * KNN + round] = mi;
    }
}

// ======================================================================
// Graph build
// ======================================================================
__global__ void count_k(const int* __restrict__ nbr, int* __restrict__ indeg)
{
    const int e = blockIdx.x * 256 + threadIdx.x;
    atomicAdd(&indeg[nbr[e]], 1);
}

__global__ __launch_bounds__(1024)
void scan_k(const int* __restrict__ indeg, int* __restrict__ offs)
{
    __shared__ int part[1024];
    const int t = threadIdx.x;
    int pre[16]; int s = 0;
    #pragma unroll
    for (int j = 0; j < 16; ++j) { pre[j] = s; s += indeg[t*16 + j]; }
    part[t] = s;
    __syncthreads();
    for (int d = 1; d < 1024; d <<= 1) {
        int v = (t >= d) ? part[t - d] : 0;
        __syncthreads();
        part[t] += v;
        __syncthreads();
    }
    const int base = (t > 0) ? part[t-1] : 0;
    #pragma unroll
    for (int j = 0; j < 16; ++j) offs[t*16 + j] = base + pre[j];
}

__global__ void fill_k(const int* __restrict__ nbr, const int* __restrict__ offs,
                       int* __restrict__ cursor, int* __restrict__ rev)
{
    const int e = blockIdx.x * 256 + threadIdx.x;
    const int v = nbr[e];
    const int i = e >> 4;
    const int p = atomicAdd(&cursor[v], 1);
    rev[offs[v] + p] = i;
}

__global__ void dinv_k(const int* __restrict__ indeg, float* __restrict__ dinv)
{
    const int v = blockIdx.x * 256 + threadIdx.x;
    dinv[v] = rsqrtf((float)(indeg[v] + KNN + 1));
}

// ======================================================================
// GCN aggregation (gather): out[v] = relu(dinv[v]*(sum m'[u]) + b)
// ======================================================================
__global__ __launch_bounds__(256)
void gather_k(const float* __restrict__ m, const int* __restrict__ nbr,
              const int* __restrict__ rev, const int* __restrict__ offs,
              const int* __restrict__ indeg, const float* __restrict__ dinv,
              const float* __restrict__ bias, float* __restrict__ outp)
{
    const int v = blockIdx.x;
    const int f = threadIdx.x;
    float acc = m[(size_t)v*DIM + f];                  // self loop
    const int* nb = &nbr[(size_t)v*KNN];
    #pragma unroll
    for (int t = 0; t < KNN; ++t) {
        const int u = nb[t];
        acc += m[(size_t)u*DIM + f];
    }
    const int o = offs[v], n = indeg[v];
    for (int t = 0; t < n; ++t) {
        const int u = rev[o + t];
        acc += m[(size_t)u*DIM + f];
    }
    const float r = dinv[v] * acc + bias[f];
    outp[(size_t)v*DIM + f] = fmaxf(r, 0.0f);
}

// ======================================================================
// FC2: pred[i,c] = hid[i,:] . Wfc2[c,:] + b[c]
// ======================================================================
__global__ void fc2_k(const float* __restrict__ hid, const float* __restrict__ W,
                      const float* __restrict__ b, float* __restrict__ out)
{
    const int g = blockIdx.x * 256 + threadIdx.x;
    if (g >= NN * 10) return;
    const int i = g / 10;
    const int c = g - i * 10;
    float acc = 0.0f;
    #pragma unroll 4
    for (int k = 0; k < 128; ++k) acc += hid[(size_t)i*128 + k] * W[c*128 + k];
    out[g] = acc + b[c];
}

// ======================================================================
extern "C" void kernel_launch(void* const* d_in, const int* in_sizes, int n_in,
                              void* d_out, int out_size, void* d_ws, size_t ws_size,
                              hipStream_t stream)
{
    const float* x     = (const float*)d_in[0];
    const float* Wpre  = (const float*)d_in[1];
    const float* bpre  = (const float*)d_in[2];
    const float* Wconv = (const float*)d_in[3];   // [2][256][256]
    const float* bconv = (const float*)d_in[4];   // [2][256]
    const float* Wfc1  = (const float*)d_in[5];   // [128][256]
    const float* bfc1  = (const float*)d_in[6];
    const float* Wfc2  = (const float*)d_in[7];   // [10][128]
    const float* bfc2  = (const float*)d_in[8];
    float* out = (float*)d_out;

    float* ws    = (float*)d_ws;
    float* h0    = ws;                               // NN*DIM
    float* mbuf  = h0    + (size_t)NN*DIM;           // NN*DIM
    float* hfbuf = mbuf  + (size_t)NN*DIM;           // NN*DIM
    float* hid   = hfbuf + (size_t)NN*DIM;           // NN*128
    float* sqv   = hid   + (size_t)NN*128;           // NN
    float* dinv  = sqv   + NN;                       // NN
    int*   nbr   = (int*)(dinv + NN);                // NN*KNN
    int*   indeg = nbr   + (size_t)NN*KNN;           // NN
    int*   offs  = indeg + NN;                       // NN
    int*   cursor= offs  + NN;                       // NN
    int*   rev   = cursor+ NN;                       // NN*KNN
    float* cand_d= (float*)(rev + (size_t)NN*KNN);   // SEG*NN*16
    int*   cand_i= (int*)(cand_d + (size_t)SEG*NN*16); // SEG*NN*16

    hipMemsetAsync(indeg,  0, NN*sizeof(int), stream);
    hipMemsetAsync(cursor, 0, NN*sizeof(int), stream);

    // 1. h0 = relu(x @ Wpre^T + bpre)
    gemm_nt<true,true,false><<<dim3(DIM/64, NN/64), 256, 0, stream>>>(
        x, Wpre, bpre, nullptr, h0, NN, DIM, DIM);
    // 2. row squared norms
    sq_kernel<<<NN/4, 256, 0, stream>>>(h0, sqv);
    // 3. exact 16-NN (segmented) + merge
    knn_topk<<<dim3(SEG, NN/128), 256, 0, stream>>>(h0, sqv, cand_d, cand_i);
    merge4_k<<<NN/64, 256, 0, stream>>>(cand_d, cand_i, nbr);
    // 4. graph build
    count_k<<<NN*KNN/256, 256, 0, stream>>>(nbr, indeg);
    scan_k<<<1, 1024, 0, stream>>>(indeg, offs);
    fill_k<<<NN*KNN/256, 256, 0, stream>>>(nbr, offs, cursor, rev);
    dinv_k<<<NN/256, 256, 0, stream>>>(indeg, dinv);
    // 5. GCN layer 1
    gemm_nt<false,false,true><<<dim3(DIM/64, NN/64), 256, 0, stream>>>(
        h0, Wconv, nullptr, dinv, mbuf, NN, DIM, DIM);
    gather_k<<<NN, 256, 0, stream>>>(mbuf, nbr, rev, offs, indeg, dinv, bconv, hfbuf);
    // 6. GCN layer 2
    gemm_nt<false,false,true><<<dim3(DIM/64, NN/64), 256, 0, stream>>>(
        hfbuf, Wconv + DIM*DIM, nullptr, dinv, h0, NN, DIM, DIM);
    gather_k<<<NN, 256, 0, stream>>>(h0, nbr, rev, offs, indeg, dinv, bconv + DIM, mbuf);
    // 7. FC1
    gemm_nt<true,true,false><<<dim3(128/64, NN/64), 256, 0, stream>>>(
        mbuf, Wfc1, bfc1, nullptr, hid, NN, DIM, 128);
    // 8. FC2
    fc2_k<<<NN*10/256, 256, 0, stream>>>(hid, Wfc2, bfc2, out);
}

// Round 4
// 1940.779 us; speedup vs baseline: 3.3760x; 1.4934x over previous
//
#include <hip/hip_runtime.h>

#define NN   16384
#define DIM  256
#define KNN  16
#define SEG  4
#define JT_PER (NN / SEG / 128)   // 32 column tiles per segment

typedef __attribute__((ext_vector_type(8))) short  bf16x8;
typedef __attribute__((ext_vector_type(4))) float  f32x4;

// ======================================================================
// async global->LDS 16B helpers (linear LDS dest, per-lane global source)
// ======================================================================
__device__ __forceinline__ void gload_lds16(const float* g, float* l)
{
    __builtin_amdgcn_global_load_lds(
        (const __attribute__((address_space(1))) unsigned int*)g,
        (__attribute__((address_space(3))) unsigned int*)l, 16, 0, 0);
}
__device__ __forceinline__ void gload_lds16b(const unsigned short* g, void* l)
{
    __builtin_amdgcn_global_load_lds(
        (const __attribute__((address_space(1))) unsigned int*)g,
        (__attribute__((address_space(3))) unsigned int*)l, 16, 0, 0);
}

// float -> bf16 (RNE, finite inputs)
__device__ __forceinline__ unsigned short f2bf(float x)
{
    unsigned int u = __float_as_uint(x);
    unsigned int r = (u + 0x7fffu + ((u >> 16) & 1u)) >> 16;
    return (unsigned short)r;
}

// ======================================================================
// Generic fp32 GEMM:  C[M,NO] = act( rowscale(A[M,K] @ W[NO,K]^T) + bias )
// BM=BN=64, TK=16, 256 threads, 4x4 micro-tile. Optional bf16 shadow copy.
// ======================================================================
template<bool RELU, bool BIAS, bool ROWSCALE, bool BF16OUT>
__global__ __launch_bounds__(256)
void gemm_nt(const float* __restrict__ A, const float* __restrict__ W,
             const float* __restrict__ bias, const float* __restrict__ rscale,
             float* __restrict__ C, unsigned short* __restrict__ Cb,
             int M, int K, int NO)
{
    __shared__ __align__(16) float As[16][68];
    __shared__ __align__(16) float Ws[16][68];
    const int tid = threadIdx.x;
    const int tx = tid & 15, ty = tid >> 4;
    const int row0 = blockIdx.y * 64, col0 = blockIdx.x * 64;
    const int lr = tid >> 2;          // 0..63
    const int lk = (tid & 3) * 4;     // 0,4,8,12

    float acc[4][4] = {};

    for (int k0 = 0; k0 < K; k0 += 16) {
        float4 av = *(const float4*)&A[(size_t)(row0 + lr) * K + k0 + lk];
        float4 wv = *(const float4*)&W[(size_t)(col0 + lr) * K + k0 + lk];
        __syncthreads();
        As[lk+0][lr] = av.x; As[lk+1][lr] = av.y; As[lk+2][lr] = av.z; As[lk+3][lr] = av.w;
        Ws[lk+0][lr] = wv.x; Ws[lk+1][lr] = wv.y; Ws[lk+2][lr] = wv.z; Ws[lk+3][lr] = wv.w;
        __syncthreads();
        #pragma unroll
        for (int kk = 0; kk < 16; ++kk) {
            float4 a = *(const float4*)&As[kk][ty*4];
            float4 b = *(const float4*)&Ws[kk][tx*4];
            acc[0][0] += a.x*b.x; acc[0][1] += a.x*b.y; acc[0][2] += a.x*b.z; acc[0][3] += a.x*b.w;
            acc[1][0] += a.y*b.x; acc[1][1] += a.y*b.y; acc[1][2] += a.y*b.z; acc[1][3] += a.y*b.w;
            acc[2][0] += a.z*b.x; acc[2][1] += a.z*b.y; acc[2][2] += a.z*b.z; acc[2][3] += a.z*b.w;
            acc[3][0] += a.w*b.x; acc[3][1] += a.w*b.y; acc[3][2] += a.w*b.z; acc[3][3] += a.w*b.w;
        }
    }

    #pragma unroll
    for (int rr = 0; rr < 4; ++rr) {
        const int r = row0 + ty*4 + rr;
        const float s = ROWSCALE ? rscale[r] : 1.0f;
        float o[4];
        #pragma unroll
        for (int cc = 0; cc < 4; ++cc) {
            float v = acc[rr][cc] * s;
            if (BIAS) v += bias[col0 + tx*4 + cc];
            if (RELU) v = fmaxf(v, 0.0f);
            o[cc] = v;
        }
        float4 ov = make_float4(o[0], o[1], o[2], o[3]);
        *(float4*)&C[(size_t)r * NO + col0 + tx*4] = ov;
        if (BF16OUT) {
            ushort4 bv;
            bv.x = f2bf(o[0]); bv.y = f2bf(o[1]);
            bv.z = f2bf(o[2]); bv.w = f2bf(o[3]);
            *(ushort4*)&Cb[(size_t)r * NO + col0 + tx*4] = bv;
        }
    }
}

// ======================================================================
// Row squared-norms: one wave per row
// ======================================================================
__global__ __launch_bounds__(256)
void sq_kernel(const float* __restrict__ h0, float* __restrict__ sq)
{
    const int wid = threadIdx.x >> 6, lane = threadIdx.x & 63;
    const int row = blockIdx.x * 4 + wid;
    float4 v = *(const float4*)&h0[(size_t)row * DIM + lane * 4];
    float s = v.x*v.x + v.y*v.y + v.z*v.z + v.w*v.w;
    #pragma unroll
    for (int o = 32; o > 0; o >>= 1) s += __shfl_down(s, o);
    if (lane == 0) sq[row] = s;
}

// ======================================================================
// Register-resident top-16 insertion network (compile-time indexed)
// ======================================================================
__device__ __forceinline__ void topk_insert(float (&dv)[16], int (&iv)[16], float d, int j)
{
    #pragma unroll
    for (int p = 15; p >= 0; --p) {
        if (d < dv[p]) {
            if (p < 15) { dv[p+1] = dv[p]; iv[p+1] = iv[p]; }
            dv[p] = d; iv[p] = j;
        }
    }
}

// ======================================================================
// kNN approx pass: bf16 MFMA 128x128 Gram tiles.
// 4 waves: (wj,wi) 2x2 grid of 64x64 sub-tiles; 16x16x32 bf16 MFMA.
// A operand = j-rows (C0 block), B operand = i-rows (R0 block) so the
// D fragment has col = lane&15 = i, rows = j (regs) -> i-major LDS dump
// gives contiguous per-i candidate reads.
// Approx keys (sq_j - 2*dot_bf16 + sq_i) feed per-(row,half) top-16.
// ======================================================================
__global__ __launch_bounds__(256, 1)
void knn_topk(const unsigned short* __restrict__ h0b, const float* __restrict__ sq,
              float* __restrict__ cand_d, int* __restrict__ cand_i)
{
    __shared__ __align__(16) float smem[16896];   // 67.6 KB
    char* sbase = (char*)smem;
    unsigned short* stA = (unsigned short*)sbase;            // i rows (R0), bf16[128][64]
    unsigned short* stB = (unsigned short*)(sbase + 16384);  // j rows (C0), bf16[128][64]
    float* D = smem;                                         // f32 [128 i][132 j]

    const int tid  = threadIdx.x;
    const int lane = tid & 63;
    const int wave = tid >> 6;
    const int wj = wave >> 1;       // j 64-block
    const int wi = wave & 1;        // i 64-block
    const int l15 = lane & 15;
    const int g   = lane >> 4;      // k-group 0..3
    const int R0 = blockIdx.y * 128;
    const int seg = blockIdx.x;

    const int orow  = tid >> 1;     // owned i (0..127)
    const int ohalf = tid & 1;
    const int myrow = R0 + orow;
    const float osq = sq[myrow];

    float dl[16]; int il[16];
    #pragma unroll
    for (int e = 0; e < 16; ++e) { dl[e] = 3e38f; il[e] = 0x7fffffff; }

    for (int jt = 0; jt < JT_PER; ++jt) {
        const int C0 = seg * (NN / SEG) + jt * 128;
        f32x4 acc[4][4];
        #pragma unroll
        for (int fa = 0; fa < 4; ++fa)
            #pragma unroll
            for (int fb = 0; fb < 4; ++fb)
                acc[fa][fb] = (f32x4){0.f, 0.f, 0.f, 0.f};

        #pragma unroll 1
        for (int ch = 0; ch < 4; ++ch) {
            const int k0g = ch * 64;
            __syncthreads();   // protect smem (D / prior stage) before overwrite
            // stage 128 rows x 64 k of bf16 per operand; LDS linear dest,
            // global source carries the k-unit XOR: LDS[row][f] = k-unit f^(row&7)
            #pragma unroll
            for (int it = 0; it < 4; ++it) {
                const int lin = tid + it * 256;       // 0..1023
                const int row = lin >> 3, f = lin & 7;
                const int kq = f ^ (row & 7);
                gload_lds16b(&h0b[(size_t)(R0 + row) * DIM + k0g + kq * 8],
                             (char*)stA + lin * 16);
                gload_lds16b(&h0b[(size_t)(C0 + row) * DIM + k0g + kq * 8],
                             (char*)stB + lin * 16);
            }
            __syncthreads();

            #pragma unroll
            for (int k0 = 0; k0 < 64; k0 += 32) {
                const int ub = (k0 >> 3) + g;         // 16B k-unit
                bf16x8 af[4], bf[4];
                #pragma unroll
                for (int fb = 0; fb < 4; ++fb) {
                    const int jr = wj*64 + fb*16 + l15;
                    const int ir = wi*64 + fb*16 + l15;
                    af[fb] = *(const bf16x8*)((char*)stB + jr*128 + ((ub ^ (jr & 7)) * 16));
                    bf[fb] = *(const bf16x8*)((char*)stA + ir*128 + ((ub ^ (ir & 7)) * 16));
                }
                #pragma unroll
                for (int fa = 0; fa < 4; ++fa)
                    #pragma unroll
                    for (int fb = 0; fb < 4; ++fb)
                        acc[fa][fb] = __builtin_amdgcn_mfma_f32_16x16x32_bf16(
                            af[fa], bf[fb], acc[fa][fb], 0, 0, 0);
            }
        }

        // dump D (i-major, stride 132): lane's 4 regs = j0..j0+3 at col i
        __syncthreads();
        #pragma unroll
        for (int fa = 0; fa < 4; ++fa) {
            #pragma unroll
            for (int fb = 0; fb < 4; ++fb) {
                const int i_ = wi*64 + fb*16 + l15;
                const int j0 = wj*64 + fa*16 + g*4;
                *(f32x4*)&D[i_ * 132 + j0] = acc[fa][fb];
            }
        }
        __syncthreads();

        // candidate phase: thread owns (orow, ohalf)
        const int cb = C0 + ohalf * 64;
        const float* Dr = &D[orow * 132 + ohalf * 64];
        #pragma clang loop unroll(disable)
        for (int e = 0; e < 16; ++e) {
            const float4 dv4 = *(const float4*)&Dr[e * 4];
            const float4 sv4 = *(const float4*)&sq[cb + e * 4];
            const int j0 = cb + e * 4;
            float d;
            d = (osq + sv4.x) - 2.0f * dv4.x;
            if (j0 + 0 != myrow && d < dl[15]) topk_insert(dl, il, d, j0 + 0);
            d = (osq + sv4.y) - 2.0f * dv4.y;
            if (j0 + 1 != myrow && d < dl[15]) topk_insert(dl, il, d, j0 + 1);
            d = (osq + sv4.z) - 2.0f * dv4.z;
            if (j0 + 2 != myrow && d < dl[15]) topk_insert(dl, il, d, j0 + 2);
            d = (osq + sv4.w) - 2.0f * dv4.w;
            if (j0 + 3 != myrow && d < dl[15]) topk_insert(dl, il, d, j0 + 3);
        }
    }

    // block-level merge: 2 half-lists per row -> sorted 16 per (seg,row)
    __syncthreads();
    float* cd = smem;
    int*   ci = (int*)(smem + 8192);
    #pragma unroll
    for (int e = 0; e < 16; ++e) {
        cd[tid * 17 + e] = dl[e];
        ci[tid * 17 + e] = il[e];
    }
    __syncthreads();
    if (tid < 128) {
        const float* LA = &cd[(2*tid) * 17];
        const float* LB = &cd[(2*tid + 1) * 17];
        const int* IA = &ci[(2*tid) * 17];
        const int* IB = &ci[(2*tid + 1) * 17];
        int pa = 0, pb = 0;
        const size_t obase = ((size_t)seg * NN + R0 + tid) * 16;
        #pragma clang loop unroll(disable)
        for (int r = 0; r < 16; ++r) {
            const float da = LA[pa], db = LB[pb];
            const int ia = IA[pa], ib = IB[pb];
            const bool takeA = (da < db) || (da == db && ia < ib);
            cand_d[obase + r] = takeA ? da : db;
            cand_i[obase + r] = takeA ? ia : ib;
            if (takeA) ++pa; else ++pb;
        }
    }
}

// ======================================================================
// Merge 4 sorted seg-lists -> approx top-32 candidate indices per row
// ======================================================================
__global__ __launch_bounds__(256)
void merge32_k(const float* __restrict__ cand_d, const int* __restrict__ cand_i,
               int* __restrict__ cand32)
{
    const int tid = threadIdx.x;
    const int row = blockIdx.x * 64 + (tid >> 2);
    const int l = tid & 3;
    int head = 0;
    for (int r = 0; r < 32; ++r) {
        const size_t base = ((size_t)l * NN + row) * 16;
        float md = (head < 16) ? cand_d[base + head] : 3e38f;
        int   mi = (head < 16) ? cand_i[base + head] : 0x7fffffff;
        int   ml = l;
        #pragma unroll
        for (int off = 1; off < 4; off <<= 1) {
            const float od = __shfl_xor(md, off);
            const int   oi = __shfl_xor(mi, off);
            const int   ol = __shfl_xor(ml, off);
            if (od < md || (od == md && oi < mi)) { md = od; mi = oi; ml = ol; }
        }
        if (ml == l) ++head;
        if (l == 0) cand32[(size_t)row * 32 + r] = mi;
    }
}

// ======================================================================
// Exact fp32 refine: 32 candidates/row -> true top-16 -> nbr
// 32 lanes per row, 8 rows per 256-block.
// ======================================================================
__global__ __launch_bounds__(256)
void refine_k(const float* __restrict__ h0, const float* __restrict__ sq,
              const int* __restrict__ cand32, int* __restrict__ nbr)
{
    const int tid = threadIdx.x;
    const int sub = tid & 31;
    const int row = blockIdx.x * 8 + (tid >> 5);
    const int j = cand32[(size_t)row * 32 + sub];
    float dot = 0.0f;
    #pragma clang loop unroll_count(4)
    for (int k = 0; k < DIM; k += 4) {
        float4 a = *(const float4*)&h0[(size_t)row * DIM + k];
        float4 b = *(const float4*)&h0[(size_t)j * DIM + k];
        dot += a.x*b.x + a.y*b.y + a.z*b.z + a.w*b.w;
    }
    float d = sq[row] + sq[j] - 2.0f * dot;
    const int ji = j;
    for (int t = 0; t < 16; ++t) {
        float md = d; int mi = ji;
        #pragma unroll
        for (int off = 1; off < 32; off <<= 1) {
            const float od = __shfl_xor(md, off);
            const int   oi = __shfl_xor(mi, off);
            if (od < md || (od == md && oi < mi)) { md = od; mi = oi; }
        }
        if (d == md && ji == mi) d = 3e38f;   // knock out winner (unique ji)
        if (sub == 0) nbr[(size_t)row * KNN + t] = mi;
    }
}

// ======================================================================
// Graph build
// ======================================================================
__global__ void count_k(const int* __restrict__ nbr, int* __restrict__ indeg)
{
    const int e = blockIdx.x * 256 + threadIdx.x;
    atomicAdd(&indeg[nbr[e]], 1);
}

__global__ __launch_bounds__(1024)
void scan_k(const int* __restrict__ indeg, int* __restrict__ offs)
{
    __shared__ int part[1024];
    const int t = threadIdx.x;
    int pre[16]; int s = 0;
    #pragma unroll
    for (int j = 0; j < 16; ++j) { pre[j] = s; s += indeg[t*16 + j]; }
    part[t] = s;
    __syncthreads();
    for (int d = 1; d < 1024; d <<= 1) {
        int v = (t >= d) ? part[t - d] : 0;
        __syncthreads();
        part[t] += v;
        __syncthreads();
    }
    const int base = (t > 0) ? part[t-1] : 0;
    #pragma unroll
    for (int j = 0; j < 16; ++j) offs[t*16 + j] = base + pre[j];
}

__global__ void fill_k(const int* __restrict__ nbr, const int* __restrict__ offs,
                       int* __restrict__ cursor, int* __restrict__ rev)
{
    const int e = blockIdx.x * 256 + threadIdx.x;
    const int v = nbr[e];
    const int i = e >> 4;
    const int p = atomicAdd(&cursor[v], 1);
    rev[offs[v] + p] = i;
}

__global__ void dinv_k(const int* __restrict__ indeg, float* __restrict__ dinv)
{
    const int v = blockIdx.x * 256 + threadIdx.x;
    dinv[v] = rsqrtf((float)(indeg[v] + KNN + 1));
}

// ======================================================================
// GCN aggregation (gather): out[v] = relu(dinv[v]*(sum m'[u]) + b)
// ======================================================================
__global__ __launch_bounds__(256)
void gather_k(const float* __restrict__ m, const int* __restrict__ nbr,
              const int* __restrict__ rev, const int* __restrict__ offs,
              const int* __restrict__ indeg, const float* __restrict__ dinv,
              const float* __restrict__ bias, float* __restrict__ outp)
{
    const int v = blockIdx.x;
    const int f = threadIdx.x;
    float acc = m[(size_t)v*DIM + f];                  // self loop
    const int* nb = &nbr[(size_t)v*KNN];
    #pragma unroll
    for (int t = 0; t < KNN; ++t) {
        const int u = nb[t];
        acc += m[(size_t)u*DIM + f];
    }
    const int o = offs[v], n = indeg[v];
    for (int t = 0; t < n; ++t) {
        const int u = rev[o + t];
        acc += m[(size_t)u*DIM + f];
    }
    const float r = dinv[v] * acc + bias[f];
    outp[(size_t)v*DIM + f] = fmaxf(r, 0.0f);
}

// ======================================================================
// FC2: pred[i,c] = hid[i,:] . Wfc2[c,:] + b[c]
// ======================================================================
__global__ void fc2_k(const float* __restrict__ hid, const float* __restrict__ W,
                      const float* __restrict__ b, float* __restrict__ out)
{
    const int g = blockIdx.x * 256 + threadIdx.x;
    if (g >= NN * 10) return;
    const int i = g / 10;
    const int c = g - i * 10;
    float acc = 0.0f;
    #pragma unroll 4
    for (int k = 0; k < 128; ++k) acc += hid[(size_t)i*128 + k] * W[c*128 + k];
    out[g] = acc + b[c];
}

// ======================================================================
extern "C" void kernel_launch(void* const* d_in, const int* in_sizes, int n_in,
                              void* d_out, int out_size, void* d_ws, size_t ws_size,
                              hipStream_t stream)
{
    const float* x     = (const float*)d_in[0];
    const float* Wpre  = (const float*)d_in[1];
    const float* bpre  = (const float*)d_in[2];
    const float* Wconv = (const float*)d_in[3];   // [2][256][256]
    const float* bconv = (const float*)d_in[4];   // [2][256]
    const float* Wfc1  = (const float*)d_in[5];   // [128][256]
    const float* bfc1  = (const float*)d_in[6];
    const float* Wfc2  = (const float*)d_in[7];   // [10][128]
    const float* bfc2  = (const float*)d_in[8];
    float* out = (float*)d_out;

    float* ws    = (float*)d_ws;
    float* h0    = ws;                               // NN*DIM
    float* mbuf  = h0    + (size_t)NN*DIM;           // NN*DIM
    float* hfbuf = mbuf  + (size_t)NN*DIM;           // NN*DIM
    float* hid   = hfbuf + (size_t)NN*DIM;           // NN*128 f32 (late) / h0b bf16 (early)
    float* sqv   = hid   + (size_t)NN*128;           // NN
    float* dinv  = sqv   + NN;                       // NN
    int*   nbr   = (int*)(dinv + NN);                // NN*KNN
    int*   indeg = nbr   + (size_t)NN*KNN;           // NN
    int*   offs  = indeg + NN;                       // NN
    int*   cursor= offs  + NN;                       // NN
    int*   rev   = cursor+ NN;                       // NN*KNN
    float* cand_d= (float*)(rev + (size_t)NN*KNN);   // SEG*NN*16
    int*   cand_i= (int*)(cand_d + (size_t)SEG*NN*16); // SEG*NN*16

    unsigned short* h0b = (unsigned short*)hid;      // NN*DIM bf16 == 8 MB (== hid size)
    int* cand32 = (int*)mbuf;                        // NN*32 int (mbuf written later)

    hipMemsetAsync(indeg,  0, NN*sizeof(int), stream);
    hipMemsetAsync(cursor, 0, NN*sizeof(int), stream);

    // 1. h0 = relu(x @ Wpre^T + bpre); fused bf16 shadow copy
    gemm_nt<true,true,false,true><<<dim3(DIM/64, NN/64), 256, 0, stream>>>(
        x, Wpre, bpre, nullptr, h0, h0b, NN, DIM, DIM);
    // 2. row squared norms (fp32)
    sq_kernel<<<NN/4, 256, 0, stream>>>(h0, sqv);
    // 3. approx 16-NN per (seg,row) via bf16 MFMA
    knn_topk<<<dim3(SEG, NN/128), 256, 0, stream>>>(h0b, sqv, cand_d, cand_i);
    // 3b. merge segs -> top-32 candidates, exact fp32 refine -> nbr
    merge32_k<<<NN/64, 256, 0, stream>>>(cand_d, cand_i, cand32);
    refine_k<<<NN/8, 256, 0, stream>>>(h0, sqv, cand32, nbr);
    // 4. graph build
    count_k<<<NN*KNN/256, 256, 0, stream>>>(nbr, indeg);
    scan_k<<<1, 1024, 0, stream>>>(indeg, offs);
    fill_k<<<NN*KNN/256, 256, 0, stream>>>(nbr, offs, cursor, rev);
    dinv_k<<<NN/256, 256, 0, stream>>>(indeg, dinv);
    // 5. GCN layer 1
    gemm_nt<false,false,true,false><<<dim3(DIM/64, NN/64), 256, 0, stream>>>(
        h0, Wconv, nullptr, dinv, mbuf, nullptr, NN, DIM, DIM);
    gather_k<<<NN, 256, 0, stream>>>(mbuf, nbr, rev, offs, indeg, dinv, bconv, hfbuf);
    // 6. GCN layer 2
    gemm_nt<false,false,true,false><<<dim3(DIM/64, NN/64), 256, 0, stream>>>(
        hfbuf, Wconv + DIM*DIM, nullptr, dinv, h0, nullptr, NN, DIM, DIM);
    gather_k<<<NN, 256, 0, stream>>>(h0, nbr, rev, offs, indeg, dinv, bconv + DIM, mbuf);
    // 7. FC1
    gemm_nt<true,true,false,false><<<dim3(128/64, NN/64), 256, 0, stream>>>(
        mbuf, Wfc1, bfc1, nullptr, hid, nullptr, NN, DIM, 128);
    // 8. FC2
    fc2_k<<<NN*10/256, 256, 0, stream>>>(hid, Wfc2, bfc2, out);
}